// Round 1
// baseline (215.187 us; speedup 1.0000x reference)
//
#include <hip/hip_runtime.h>

#define EMB 256
#define HD 32
#define SEQ 4096

typedef _Float16 half8 __attribute__((ext_vector_type(8)));
typedef float floatx4 __attribute__((ext_vector_type(4)));

#define L2E 1.44269504088896340736f

// ---------------- Kernel 0: transpose W (3x [256][32] f32) -> Wt (3x [32][256] f16) ----------------
__global__ __launch_bounds__(256) void wt_kernel(const float* __restrict__ Wq,
                                                 const float* __restrict__ Wk,
                                                 const float* __restrict__ Wv,
                                                 _Float16* __restrict__ wt) {
  int gid = blockIdx.x * 256 + threadIdx.x;   // [0, 3072)
  if (gid >= 3072) return;
  int mat = gid >> 10;            // 0..2
  int rem = gid & 1023;
  int d   = rem >> 5;             // 0..31
  int ec  = rem & 31;             // 0..31 -> e chunk of 8
  const float* W = (mat == 0) ? Wq : ((mat == 1) ? Wk : Wv);
  _Float16* dst = wt + mat * (HD * EMB) + d * EMB + ec * 8;
#pragma unroll
  for (int j = 0; j < 8; ++j) dst[j] = (_Float16)W[(ec * 8 + j) * HD + d];
}

// ---------------- Kernel 1: QKV projection via MFMA ----------------
// grid 256 blocks x 256 thr; wave handles 16 rows; K=256 in 8 chunks of 32.
__global__ __launch_bounds__(256) void qkv_kernel(const float* __restrict__ x,
                                                  const _Float16* __restrict__ wt,
                                                  _Float16* __restrict__ qw,
                                                  _Float16* __restrict__ kw,
                                                  _Float16* __restrict__ vw) {
  int wave = threadIdx.x >> 6;
  int lane = threadIdx.x & 63;
  int n = lane & 15, quad = lane >> 4;
  int rowbase = blockIdx.x * 64 + wave * 16;
  int arow = rowbase + n;

  floatx4 aq0 = {0,0,0,0}, aq1 = {0,0,0,0};
  floatx4 ak0 = {0,0,0,0}, ak1 = {0,0,0,0};
  floatx4 av0 = {0,0,0,0}, av1 = {0,0,0,0};

#pragma unroll
  for (int kc = 0; kc < 8; ++kc) {
    const float* xp = x + arow * EMB + kc * 32 + quad * 8;
    float4 xa = *(const float4*)(xp);
    float4 xb = *(const float4*)(xp + 4);
    half8 a;
    a[0] = (_Float16)xa.x; a[1] = (_Float16)xa.y; a[2] = (_Float16)xa.z; a[3] = (_Float16)xa.w;
    a[4] = (_Float16)xb.x; a[5] = (_Float16)xb.y; a[6] = (_Float16)xb.z; a[7] = (_Float16)xb.w;
    const _Float16* wb = wt + kc * 32 + quad * 8;
    half8 bq0 = *(const half8*)(wb + (0 * HD + n)      * EMB);
    half8 bq1 = *(const half8*)(wb + (0 * HD + n + 16) * EMB);
    half8 bk0 = *(const half8*)(wb + (1 * HD + n)      * EMB);
    half8 bk1 = *(const half8*)(wb + (1 * HD + n + 16) * EMB);
    half8 bv0 = *(const half8*)(wb + (2 * HD + n)      * EMB);
    half8 bv1 = *(const half8*)(wb + (2 * HD + n + 16) * EMB);
    aq0 = __builtin_amdgcn_mfma_f32_16x16x32_f16(a, bq0, aq0, 0, 0, 0);
    aq1 = __builtin_amdgcn_mfma_f32_16x16x32_f16(a, bq1, aq1, 0, 0, 0);
    ak0 = __builtin_amdgcn_mfma_f32_16x16x32_f16(a, bk0, ak0, 0, 0, 0);
    ak1 = __builtin_amdgcn_mfma_f32_16x16x32_f16(a, bk1, ak1, 0, 0, 0);
    av0 = __builtin_amdgcn_mfma_f32_16x16x32_f16(a, bv0, av0, 0, 0, 0);
    av1 = __builtin_amdgcn_mfma_f32_16x16x32_f16(a, bv1, av1, 0, 0, 0);
  }
  // C/D layout: col = lane&15, row = quad*4 + r
#pragma unroll
  for (int r = 0; r < 4; ++r) {
    int row = rowbase + quad * 4 + r;
    qw[row * HD + n]      = (_Float16)aq0[r];
    qw[row * HD + n + 16] = (_Float16)aq1[r];
    kw[row * HD + n]      = (_Float16)ak0[r];
    kw[row * HD + n + 16] = (_Float16)ak1[r];
    vw[row * HD + n]      = (_Float16)av0[r];
    vw[row * HD + n + 16] = (_Float16)av1[r];
  }
}

// ---------------- Kernel 2: flash attention ----------------
// grid 512 blocks x 128 thr (2 waves). Block: 32 q-rows (wave=16), loops 64-key tiles.
__global__ __launch_bounds__(128) void attn_kernel(const _Float16* __restrict__ q,
                                                   const _Float16* __restrict__ k,
                                                   const _Float16* __restrict__ v,
                                                   float* __restrict__ out) {
  __shared__ _Float16 Kt[64 * 32];        // [key][dim], rows 64B
  __shared__ _Float16 Vt[32 * 72];        // [dim][key], stride 72 (144B rows, 16B aligned)
  __shared__ _Float16 Pl[2][16 * 72];     // per-wave P, [qrow][key], stride 72

  int t = threadIdx.x;
  int wave = t >> 6, lane = t & 63;
  int n = lane & 15, quad = lane >> 4;
  int b  = blockIdx.x >> 7;
  int qt = blockIdx.x & 127;
  int qrowg = b * SEQ + qt * 32 + wave * 16;

  // Q A-frag: A[m=lane&15][kk=quad*8+j], head dim 32 = one K-chunk
  half8 qf = *(const half8*)(q + (qrowg + n) * HD + quad * 8);

  floatx4 o0 = {0,0,0,0}, o1 = {0,0,0,0};
  float mr[4] = {-__builtin_huge_valf(), -__builtin_huge_valf(),
                 -__builtin_huge_valf(), -__builtin_huge_valf()};
  float lr[4] = {0.f, 0.f, 0.f, 0.f};
  const floatx4 zero = {0,0,0,0};

  const _Float16* kb0 = k + b * SEQ * HD;
  const _Float16* vb0 = v + b * SEQ * HD;

  for (int kt = 0; kt < 64; ++kt) {
    __syncthreads();   // protect Kt/Vt from previous iteration's readers
    // stage K tile (64x32), coalesced 16B copies
    const _Float16* kbase = kb0 + kt * 64 * HD;
    const _Float16* vbase = vb0 + kt * 64 * HD;
#pragma unroll
    for (int i = 0; i < 2; ++i) {
      int idx = (i * 128 + t) * 8;
      *(uint4*)&Kt[idx] = *(const uint4*)&kbase[idx];
    }
    // stage V transposed: unit u -> row=u&63 (== lane), dim group = u>>6 (wave-uniform)
#pragma unroll
    for (int i = 0; i < 2; ++i) {
      int u = i * 128 + t;
      int row = u & 63, dg = u >> 6;
      half8 raw = *(const half8*)&vbase[row * HD + dg * 8];
#pragma unroll
      for (int j = 0; j < 8; ++j) Vt[(dg * 8 + j) * 72 + row] = raw[j];
    }
    __syncthreads();

    // QK^T: scores S[16 q x 64 keys] in 4 frags (16 keys each)
    floatx4 s[4];
#pragma unroll
    for (int g = 0; g < 4; ++g) {
      half8 bk = *(const half8*)&Kt[(g * 16 + n) * 32 + quad * 8];
      s[g] = __builtin_amdgcn_mfma_f32_16x16x32_f16(qf, bk, zero, 0, 0, 0);
    }

    // online softmax per accumulator row r (qrow = quad*4 + r)
#pragma unroll
    for (int r = 0; r < 4; ++r) {
      float smax = fmaxf(fmaxf(s[0][r], s[1][r]), fmaxf(s[2][r], s[3][r]));
#pragma unroll
      for (int off = 1; off <= 8; off <<= 1) smax = fmaxf(smax, __shfl_xor(smax, off));
      float mnew = fmaxf(mr[r], smax);
      float alpha = __builtin_amdgcn_exp2f((mr[r] - mnew) * L2E);
      float c = mnew * L2E;
      float p0 = __builtin_amdgcn_exp2f(s[0][r] * L2E - c);
      float p1 = __builtin_amdgcn_exp2f(s[1][r] * L2E - c);
      float p2 = __builtin_amdgcn_exp2f(s[2][r] * L2E - c);
      float p3 = __builtin_amdgcn_exp2f(s[3][r] * L2E - c);
      float psum = (p0 + p1) + (p2 + p3);
#pragma unroll
      for (int off = 1; off <= 8; off <<= 1) psum += __shfl_xor(psum, off);
      lr[r] = lr[r] * alpha + psum;
      o0[r] *= alpha;
      o1[r] *= alpha;
      mr[r] = mnew;
      int prow = (quad * 4 + r) * 72;
      Pl[wave][prow +      n] = (_Float16)p0;
      Pl[wave][prow + 16 + n] = (_Float16)p1;
      Pl[wave][prow + 32 + n] = (_Float16)p2;
      Pl[wave][prow + 48 + n] = (_Float16)p3;
    }

    // P: C-layout -> A-layout via LDS (per-wave buffer, no barrier needed)
    half8 a0 = *(const half8*)&Pl[wave][n * 72 + quad * 8];        // keys 0..31
    half8 a1 = *(const half8*)&Pl[wave][n * 72 + 32 + quad * 8];   // keys 32..63
    // V B-frags: B[kk=key][nn=dim] = Vt[dim][key]
    half8 v00 = *(const half8*)&Vt[n * 72 + quad * 8];
    half8 v01 = *(const half8*)&Vt[n * 72 + 32 + quad * 8];
    half8 v10 = *(const half8*)&Vt[(n + 16) * 72 + quad * 8];
    half8 v11 = *(const half8*)&Vt[(n + 16) * 72 + 32 + quad * 8];
    o0 = __builtin_amdgcn_mfma_f32_16x16x32_f16(a0, v00, o0, 0, 0, 0);
    o0 = __builtin_amdgcn_mfma_f32_16x16x32_f16(a1, v01, o0, 0, 0, 0);
    o1 = __builtin_amdgcn_mfma_f32_16x16x32_f16(a0, v10, o1, 0, 0, 0);
    o1 = __builtin_amdgcn_mfma_f32_16x16x32_f16(a1, v11, o1, 0, 0, 0);
  }

  // epilogue: out = O * scaling / l   (post-softmax scaling!)
  const float scaling = 0.17677669529663687f;  // 32^-0.5
#pragma unroll
  for (int r = 0; r < 4; ++r) {
    float inv = scaling / lr[r];
    int row = qrowg + quad * 4 + r;
    out[row * HD + n]      = o0[r] * inv;
    out[row * HD + n + 16] = o1[r] * inv;
  }
}

extern "C" void kernel_launch(void* const* d_in, const int* in_sizes, int n_in,
                              void* d_out, int out_size, void* d_ws, size_t ws_size,
                              hipStream_t stream) {
  const float* x  = (const float*)d_in[0];
  const float* Wq = (const float*)d_in[1];
  const float* Wk = (const float*)d_in[2];
  const float* Wv = (const float*)d_in[3];
  float* out = (float*)d_out;

  _Float16* wt = (_Float16*)d_ws;          // 3*32*256   = 24576 f16
  _Float16* qw = wt + 3 * HD * EMB;        // 16384*32   = 524288 f16
  _Float16* kw = qw + 16384 * HD;
  _Float16* vw = kw + 16384 * HD;          // total ~3.05 MB of ws

  wt_kernel<<<12, 256, 0, stream>>>(Wq, Wk, Wv, wt);
  qkv_kernel<<<256, 256, 0, stream>>>(x, wt, qw, kw, vw);
  attn_kernel<<<512, 128, 0, stream>>>(qw, kw, vw, out);
}

// Round 2
// 124.273 us; speedup vs baseline: 1.7316x; 1.7316x over previous
//
#include <hip/hip_runtime.h>

#define EMB 256
#define HD 32
#define SEQ 4096

typedef _Float16 half8 __attribute__((ext_vector_type(8)));
typedef _Float16 half4 __attribute__((ext_vector_type(4)));
typedef float floatx4 __attribute__((ext_vector_type(4)));

#define L2E 1.44269504088896340736f

// max over 16-lane rows via DPP row_ror (VALU pipe only — no LDS swizzles)
__device__ __forceinline__ float rowmax16(float x) {
  int xi = __builtin_bit_cast(int, x);
  float t;
  t = __builtin_bit_cast(float, __builtin_amdgcn_update_dpp(xi, xi, 0x121, 0xf, 0xf, false));
  x = fmaxf(x, t); xi = __builtin_bit_cast(int, x);
  t = __builtin_bit_cast(float, __builtin_amdgcn_update_dpp(xi, xi, 0x122, 0xf, 0xf, false));
  x = fmaxf(x, t); xi = __builtin_bit_cast(int, x);
  t = __builtin_bit_cast(float, __builtin_amdgcn_update_dpp(xi, xi, 0x124, 0xf, 0xf, false));
  x = fmaxf(x, t); xi = __builtin_bit_cast(int, x);
  t = __builtin_bit_cast(float, __builtin_amdgcn_update_dpp(xi, xi, 0x128, 0xf, 0xf, false));
  x = fmaxf(x, t);
  return x;
}

// ---------------- Kernel 0: transpose W (3x [256][32] f32) -> Wt (3x [32][256] f16) ----------------
__global__ __launch_bounds__(256) void wt_kernel(const float* __restrict__ Wq,
                                                 const float* __restrict__ Wk,
                                                 const float* __restrict__ Wv,
                                                 _Float16* __restrict__ wt) {
  int gid = blockIdx.x * 256 + threadIdx.x;   // [0, 3072)
  if (gid >= 3072) return;
  int mat = gid >> 10;
  int rem = gid & 1023;
  int d   = rem >> 5;
  int ec  = rem & 31;
  const float* W = (mat == 0) ? Wq : ((mat == 1) ? Wk : Wv);
  _Float16* dst = wt + mat * (HD * EMB) + d * EMB + ec * 8;
#pragma unroll
  for (int j = 0; j < 8; ++j) dst[j] = (_Float16)W[(ec * 8 + j) * HD + d];
}

// ---------------- Kernel 1: QKV projection (grid (256,3): y = matrix) ----------------
// mat 0 -> qw [s][d], mat 1 -> kw [s][d], mat 2 -> vt [d][s] (transposed for attn B-frags)
__global__ __launch_bounds__(256) void qkv_kernel(const float* __restrict__ x,
                                                  const _Float16* __restrict__ wt,
                                                  _Float16* __restrict__ qw,
                                                  _Float16* __restrict__ kw,
                                                  _Float16* __restrict__ vt) {
  int wave = threadIdx.x >> 6;
  int lane = threadIdx.x & 63;
  int n = lane & 15, quad = lane >> 4;
  int mat = blockIdx.y;
  int rowbase = blockIdx.x * 64 + wave * 16;
  int arow = rowbase + n;

  const _Float16* wb0 = wt + mat * (HD * EMB);
  floatx4 c0 = {0,0,0,0}, c1 = {0,0,0,0};

#pragma unroll
  for (int kc = 0; kc < 8; ++kc) {
    const float* xp = x + arow * EMB + kc * 32 + quad * 8;
    float4 xa = *(const float4*)(xp);
    float4 xb = *(const float4*)(xp + 4);
    half8 a;
    a[0] = (_Float16)xa.x; a[1] = (_Float16)xa.y; a[2] = (_Float16)xa.z; a[3] = (_Float16)xa.w;
    a[4] = (_Float16)xb.x; a[5] = (_Float16)xb.y; a[6] = (_Float16)xb.z; a[7] = (_Float16)xb.w;
    half8 b0 = *(const half8*)(wb0 + n * EMB + kc * 32 + quad * 8);
    half8 b1 = *(const half8*)(wb0 + (n + 16) * EMB + kc * 32 + quad * 8);
    c0 = __builtin_amdgcn_mfma_f32_16x16x32_f16(a, b0, c0, 0, 0, 0);
    c1 = __builtin_amdgcn_mfma_f32_16x16x32_f16(a, b1, c1, 0, 0, 0);
  }

  if (mat == 2) {
    int b = rowbase >> 12;
    int s0 = rowbase & (SEQ - 1);
    _Float16* vb = vt + b * HD * SEQ;
#pragma unroll
    for (int r = 0; r < 4; ++r) {
      int s = s0 + quad * 4 + r;
      vb[n * SEQ + s]        = (_Float16)c0[r];
      vb[(n + 16) * SEQ + s] = (_Float16)c1[r];
    }
  } else {
    _Float16* dst = (mat == 0) ? qw : kw;
#pragma unroll
    for (int r = 0; r < 4; ++r) {
      int row = rowbase + quad * 4 + r;
      dst[row * HD + n]      = (_Float16)c0[r];
      dst[row * HD + n + 16] = (_Float16)c1[r];
    }
  }
}

// ---------------- Kernel 2: flash attention, in-block split-K x4 ----------------
// 1024 blocks x 256 thr (4 waves). Block owns 16 q-rows; wave w handles keys
// [w*1024, (w+1)*1024) as 16 tiles of 64. No barriers in hot loop: K and V^T are
// read straight from global in MFMA B-frag layout (16B/lane coalesced).
__global__ __launch_bounds__(256, 4) void attn_kernel(const _Float16* __restrict__ q,
                                                      const _Float16* __restrict__ k,
                                                      const _Float16* __restrict__ vt,
                                                      float* __restrict__ out) {
  __shared__ float Om[4][16][32];
  __shared__ float Mm[4][16];
  __shared__ float Lm[4][16];
  __shared__ _Float16 Pl[4][16 * 68];   // stride 68 f16: conflict-free b16 scatter writes

  const int t = threadIdx.x;
  const int w = t >> 6, lane = t & 63;
  const int n = lane & 15, quad = lane >> 4;
  const int b  = blockIdx.x >> 8;
  const int qt = blockIdx.x & 255;
  const int qrow0 = b * SEQ + qt * 16;

  // Q A-frag: A[m = lane&15][kk = quad*8+j]
  half8 qf = *(const half8*)(q + (qrow0 + n) * HD + quad * 8);

  const _Float16* kb = k  + (size_t)b * SEQ * HD + w * 1024 * HD;
  const _Float16* vb = vt + (size_t)b * HD * SEQ + w * 1024;

  floatx4 o0 = {0,0,0,0}, o1 = {0,0,0,0}, ol = {0,0,0,0};
  float mr[4] = {-__builtin_huge_valf(), -__builtin_huge_valf(),
                 -__builtin_huge_valf(), -__builtin_huge_valf()};
  const floatx4 zero = {0,0,0,0};

  // ones-column B-frag: B[kk][0] = 1 -> row-sums (l) accumulate in column 0 via MFMA
  half8 bone = {0,0,0,0,0,0,0,0};
  if (n == 0) { bone[0]=1; bone[1]=1; bone[2]=1; bone[3]=1; bone[4]=1; bone[5]=1; bone[6]=1; bone[7]=1; }

  _Float16* pw = &Pl[w][0];

  for (int kt = 0; kt < 16; ++kt) {
    const _Float16* kt0 = kb + kt * 64 * HD;
    // QK^T: 4 frags of 16 keys, K loaded directly in B-frag layout
    floatx4 s[4];
#pragma unroll
    for (int g = 0; g < 4; ++g) {
      half8 bk = *(const half8*)(kt0 + (g * 16 + n) * HD + quad * 8);
      s[g] = __builtin_amdgcn_mfma_f32_16x16x32_f16(qf, bk, zero, 0, 0, 0);
    }

    // online softmax; row = quad*4 + r
#pragma unroll
    for (int r = 0; r < 4; ++r) {
      float smax = fmaxf(fmaxf(s[0][r], s[1][r]), fmaxf(s[2][r], s[3][r]));
      smax = rowmax16(smax);
      float mnew = fmaxf(mr[r], smax);
      float alpha = __builtin_amdgcn_exp2f((mr[r] - mnew) * L2E);
      float c = mnew * L2E;
      float p0 = __builtin_amdgcn_exp2f(s[0][r] * L2E - c);
      float p1 = __builtin_amdgcn_exp2f(s[1][r] * L2E - c);
      float p2 = __builtin_amdgcn_exp2f(s[2][r] * L2E - c);
      float p3 = __builtin_amdgcn_exp2f(s[3][r] * L2E - c);
      o0[r] *= alpha; o1[r] *= alpha; ol[r] *= alpha;
      mr[r] = mnew;
      int prow = (quad * 4 + r) * 68;
      pw[prow + n]      = (_Float16)p0;
      pw[prow + 16 + n] = (_Float16)p1;
      pw[prow + 32 + n] = (_Float16)p2;
      pw[prow + 48 + n] = (_Float16)p3;
    }

    // P: C-layout -> A-layout via per-wave LDS (wave-synchronous, no barrier)
    int pbase = n * 68 + quad * 8;
    half4 a0l = *(const half4*)(pw + pbase);
    half4 a0h = *(const half4*)(pw + pbase + 4);
    half4 a1l = *(const half4*)(pw + pbase + 32);
    half4 a1h = *(const half4*)(pw + pbase + 36);
    half8 a0, a1;
    a0[0]=a0l[0]; a0[1]=a0l[1]; a0[2]=a0l[2]; a0[3]=a0l[3];
    a0[4]=a0h[0]; a0[5]=a0h[1]; a0[6]=a0h[2]; a0[7]=a0h[3];
    a1[0]=a1l[0]; a1[1]=a1l[1]; a1[2]=a1l[2]; a1[3]=a1l[3];
    a1[4]=a1h[0]; a1[5]=a1h[1]; a1[6]=a1h[2]; a1[7]=a1h[3];

    // V^T B-frags: direct global, 16B/lane
    const _Float16* vt0 = vb + kt * 64;
    half8 v00 = *(const half8*)(vt0 + n * SEQ + quad * 8);
    half8 v01 = *(const half8*)(vt0 + n * SEQ + 32 + quad * 8);
    half8 v10 = *(const half8*)(vt0 + (n + 16) * SEQ + quad * 8);
    half8 v11 = *(const half8*)(vt0 + (n + 16) * SEQ + 32 + quad * 8);

    o0 = __builtin_amdgcn_mfma_f32_16x16x32_f16(a0, v00, o0, 0, 0, 0);
    o0 = __builtin_amdgcn_mfma_f32_16x16x32_f16(a1, v01, o0, 0, 0, 0);
    o1 = __builtin_amdgcn_mfma_f32_16x16x32_f16(a0, v10, o1, 0, 0, 0);
    o1 = __builtin_amdgcn_mfma_f32_16x16x32_f16(a1, v11, o1, 0, 0, 0);
    ol = __builtin_amdgcn_mfma_f32_16x16x32_f16(a0, bone, ol, 0, 0, 0);
    ol = __builtin_amdgcn_mfma_f32_16x16x32_f16(a1, bone, ol, 0, 0, 0);
  }

  // publish per-wave partials
#pragma unroll
  for (int r = 0; r < 4; ++r) {
    int row = quad * 4 + r;
    Om[w][row][n]      = o0[r];
    Om[w][row][n + 16] = o1[r];
    if (n == 0) { Mm[w][row] = mr[r]; Lm[w][row] = ol[r]; }
  }
  __syncthreads();

  // combine 4 partials; 512 outputs over 256 threads
  const float scaling = 0.17677669529663687f;  // 32^-0.5
#pragma unroll
  for (int e = t; e < 512; e += 256) {
    int row = e >> 5, d = e & 31;
    float m0 = Mm[0][row], m1 = Mm[1][row], m2 = Mm[2][row], m3 = Mm[3][row];
    float ms = fmaxf(fmaxf(m0, m1), fmaxf(m2, m3));
    float w0 = __builtin_amdgcn_exp2f((m0 - ms) * L2E);
    float w1 = __builtin_amdgcn_exp2f((m1 - ms) * L2E);
    float w2 = __builtin_amdgcn_exp2f((m2 - ms) * L2E);
    float w3 = __builtin_amdgcn_exp2f((m3 - ms) * L2E);
    float L = w0 * Lm[0][row] + w1 * Lm[1][row] + w2 * Lm[2][row] + w3 * Lm[3][row];
    float O = w0 * Om[0][row][d] + w1 * Om[1][row][d] + w2 * Om[2][row][d] + w3 * Om[3][row][d];
    out[(qrow0 + row) * HD + d] = O * scaling / L;
  }
}

extern "C" void kernel_launch(void* const* d_in, const int* in_sizes, int n_in,
                              void* d_out, int out_size, void* d_ws, size_t ws_size,
                              hipStream_t stream) {
  const float* x  = (const float*)d_in[0];
  const float* Wq = (const float*)d_in[1];
  const float* Wk = (const float*)d_in[2];
  const float* Wv = (const float*)d_in[3];
  float* out = (float*)d_out;

  _Float16* wt = (_Float16*)d_ws;          // 3*32*256 f16
  _Float16* qw = wt + 3 * HD * EMB;        // [16384][32]
  _Float16* kw = qw + 16384 * HD;          // [16384][32]
  _Float16* vt = kw + 16384 * HD;          // [4][32][4096] transposed

  wt_kernel<<<12, 256, 0, stream>>>(Wq, Wk, Wv, wt);
  qkv_kernel<<<dim3(256, 3), 256, 0, stream>>>(x, wt, qw, kw, vt);
  attn_kernel<<<1024, 256, 0, stream>>>(qw, kw, vt, out);
}

// Round 3
// 123.330 us; speedup vs baseline: 1.7448x; 1.0076x over previous
//
#include <hip/hip_runtime.h>

#define EMB 256
#define HD 32
#define SEQ 4096

typedef _Float16 half8 __attribute__((ext_vector_type(8)));
typedef _Float16 half4v __attribute__((ext_vector_type(4)));
typedef float floatx4 __attribute__((ext_vector_type(4)));

#define L2E 1.44269504088896340736f
#define SCALING 0.17677669529663687f   // 32^-0.5, applied POST-softmax

// ---------------- Kernel 0: swizzle W into MFMA B-frag order (f16), Wq pre-scaled by L2E ----------------
// wsw[mat][half][kc][lane][8]: B[kk=quad*8+j][nn=n+half*16] for K-chunk kc.
__global__ __launch_bounds__(256) void prep_kernel(const float* __restrict__ Wq,
                                                   const float* __restrict__ Wk,
                                                   const float* __restrict__ Wv,
                                                   _Float16* __restrict__ wsw) {
  int gid = blockIdx.x * 256 + threadIdx.x;   // [0, 24576)
  int j    = gid & 7;
  int lane = (gid >> 3) & 63;
  int kc   = (gid >> 9) & 7;
  int half = (gid >> 12) & 1;
  int mat  = gid >> 13;
  const float* W = (mat == 0) ? Wq : ((mat == 1) ? Wk : Wv);
  int n = lane & 15, quad = lane >> 4;
  int e = kc * 32 + quad * 8 + j;
  int d = n + half * 16;
  float v = W[e * HD + d];
  if (mat == 0) v *= L2E;                     // exp2-domain scores for free
  wsw[gid] = (_Float16)v;
}

// ---------------- Kernel 1: QKV projection, one pass over x, coalesced B-frags ----------------
// 256 blocks x 256 thr; wave owns 16 rows; writes q,k row-major [s][32] and v transposed [b][d][s].
__global__ __launch_bounds__(256) void qkv_kernel(const float* __restrict__ x,
                                                  const _Float16* __restrict__ wsw,
                                                  _Float16* __restrict__ qw,
                                                  _Float16* __restrict__ kw,
                                                  _Float16* __restrict__ vt) {
  int lane = threadIdx.x & 63, wave = threadIdx.x >> 6;
  int n = lane & 15, quad = lane >> 4;
  int rowbase = blockIdx.x * 64 + wave * 16;

  floatx4 c[3][2];
#pragma unroll
  for (int m = 0; m < 3; ++m)
#pragma unroll
    for (int h = 0; h < 2; ++h) c[m][h] = (floatx4){0, 0, 0, 0};

#pragma unroll
  for (int kc = 0; kc < 8; ++kc) {
    const float* xp = x + (rowbase + n) * EMB + kc * 32 + quad * 8;
    float4 xa = *(const float4*)(xp);
    float4 xb = *(const float4*)(xp + 4);
    half8 a;
    a[0] = (_Float16)xa.x; a[1] = (_Float16)xa.y; a[2] = (_Float16)xa.z; a[3] = (_Float16)xa.w;
    a[4] = (_Float16)xb.x; a[5] = (_Float16)xb.y; a[6] = (_Float16)xb.z; a[7] = (_Float16)xb.w;
#pragma unroll
    for (int m = 0; m < 3; ++m)
#pragma unroll
      for (int h = 0; h < 2; ++h) {
        half8 bb = *(const half8*)(wsw + (((m * 2 + h) * 8 + kc) << 9) + (lane << 3));
        c[m][h] = __builtin_amdgcn_mfma_f32_16x16x32_f16(a, bb, c[m][h], 0, 0, 0);
      }
  }

#pragma unroll
  for (int r = 0; r < 4; ++r) {
    int row = rowbase + quad * 4 + r;
    qw[row * HD + n]      = (_Float16)c[0][0][r];
    qw[row * HD + n + 16] = (_Float16)c[0][1][r];
    kw[row * HD + n]      = (_Float16)c[1][0][r];
    kw[row * HD + n + 16] = (_Float16)c[1][1][r];
  }
  int b = rowbase >> 12;
  int s0 = rowbase & (SEQ - 1);
  _Float16* vb = vt + b * HD * SEQ;
#pragma unroll
  for (int r = 0; r < 4; ++r) {
    int s = s0 + quad * 4 + r;
    vb[n * SEQ + s]        = (_Float16)c[2][0][r];
    vb[(n + 16) * SEQ + s] = (_Float16)c[2][1][r];
  }
}

// ---------------- Kernel 2: flash attention, S^T orientation, cross-block split-K x2 ----------------
// grid 2048 (1024 q-tiles x 2 key-halves) x 256 thr (4 waves). Wave owns 512 keys (8 tiles of 64).
// S^T = K.Q^T: lane holds 16 scores of ONE q-row (col=n) -> one softmax chain per lane.
__global__ __launch_bounds__(256, 8) void attn_kernel(const _Float16* __restrict__ q,
                                                      const _Float16* __restrict__ k,
                                                      const _Float16* __restrict__ vt,
                                                      float* __restrict__ Op,
                                                      float* __restrict__ Mp,
                                                      float* __restrict__ Lp) {
  __shared__ __align__(16) _Float16 Pl[4][16 * 72];  // P[qrow][key], per-wave
  __shared__ __align__(16) float Al[4][4][16];       // 4 identical alpha copies (conflict-free)
  __shared__ float Om[4][16][32];
  __shared__ float Mm[4][16];
  __shared__ float Lm[4][16];

  const int t = threadIdx.x;
  const int w = t >> 6, lane = t & 63;
  const int n = lane & 15, quad = lane >> 4;
  const int qt   = blockIdx.x & 1023;   // global q-tile (16 rows each)
  const int half = blockIdx.x >> 10;
  const int b = qt >> 8;
  const int qrow0 = qt * 16;
  const int key0 = half * 2048 + w * 512;

  const _Float16* kb = k  + ((size_t)b * SEQ + key0) * HD;
  const _Float16* vb = vt + (size_t)b * HD * SEQ + key0;

  // Q B-frag: B[kk=quad*8+j][nn=n] = q[qrow0+n][quad*8+j] (pre-scaled by L2E)
  half8 qf = *(const half8*)(q + (qrow0 + n) * HD + quad * 8);

  floatx4 o0 = {0,0,0,0}, o1 = {0,0,0,0}, ol = {0,0,0,0};
  float mr = -__builtin_huge_valf();
  const floatx4 zero = {0,0,0,0};

  half8 bone = {0,0,0,0,0,0,0,0};   // ones in column 0 -> MFMA row-sums for l
  if (n == 0) { bone[0]=1; bone[1]=1; bone[2]=1; bone[3]=1; bone[4]=1; bone[5]=1; bone[6]=1; bone[7]=1; }

  _Float16* pw = &Pl[w][0];

  for (int kt = 0; kt < 8; ++kt) {
    const _Float16* kt0 = kb + kt * 64 * HD;
    // S^T tiles: A = K-frag (m=key), B = Q-frag (n=qrow); C: row=key_local, col=qrow
    floatx4 s0v = __builtin_amdgcn_mfma_f32_16x16x32_f16(*(const half8*)(kt0 + (n) * HD + quad * 8),      qf, zero, 0, 0, 0);
    floatx4 s1v = __builtin_amdgcn_mfma_f32_16x16x32_f16(*(const half8*)(kt0 + (16 + n) * HD + quad * 8), qf, zero, 0, 0, 0);
    floatx4 s2v = __builtin_amdgcn_mfma_f32_16x16x32_f16(*(const half8*)(kt0 + (32 + n) * HD + quad * 8), qf, zero, 0, 0, 0);
    floatx4 s3v = __builtin_amdgcn_mfma_f32_16x16x32_f16(*(const half8*)(kt0 + (48 + n) * HD + quad * 8), qf, zero, 0, 0, 0);

    // per-lane max over this lane's 16 scores (all belong to q-row n)
    floatx4 t01 = __builtin_elementwise_max(s0v, s1v);
    floatx4 t23 = __builtin_elementwise_max(s2v, s3v);
    floatx4 t4  = __builtin_elementwise_max(t01, t23);
    float mm = fmaxf(fmaxf(t4[0], t4[1]), fmaxf(t4[2], t4[3]));
    mm = fmaxf(mm, __shfl_xor(mm, 16));
    mm = fmaxf(mm, __shfl_xor(mm, 32));
    float mnew = fmaxf(mr, mm);
    float alpha = __builtin_amdgcn_exp2f(mr - mnew);   // exp2 domain
    mr = mnew;

    floatx4 mb = {mnew, mnew, mnew, mnew};
    s0v -= mb; s1v -= mb; s2v -= mb; s3v -= mb;
    // p = exp2(s), pack 4 consecutive keys -> one b64 LDS write per 16-key group
    half4v p0, p1, p2, p3;
#pragma unroll
    for (int r = 0; r < 4; ++r) {
      p0[r] = (_Float16)__builtin_amdgcn_exp2f(s0v[r]);
      p1[r] = (_Float16)__builtin_amdgcn_exp2f(s1v[r]);
      p2[r] = (_Float16)__builtin_amdgcn_exp2f(s2v[r]);
      p3[r] = (_Float16)__builtin_amdgcn_exp2f(s3v[r]);
    }
    int pbase = n * 72 + quad * 4;
    *(half4v*)(pw + pbase)      = p0;
    *(half4v*)(pw + pbase + 16) = p1;
    *(half4v*)(pw + pbase + 32) = p2;
    *(half4v*)(pw + pbase + 48) = p3;

    // alpha: lane(row=n) -> rows quad*4+r of the o-accumulator (C-layout). 4 identical copies.
    Al[w][quad][n] = alpha;
    floatx4 av = *(const floatx4*)(&Al[w][quad][quad * 4]);
    o0 *= av; o1 *= av; ol *= av;

    // P A-frags (keys contiguous per row)
    half8 a0 = *(const half8*)(pw + n * 72 + quad * 8);
    half8 a1 = *(const half8*)(pw + n * 72 + 32 + quad * 8);
    // V^T B-frags direct from global
    const _Float16* vt0 = vb + kt * 64;
    half8 v00 = *(const half8*)(vt0 + n * SEQ + quad * 8);
    half8 v01 = *(const half8*)(vt0 + n * SEQ + 32 + quad * 8);
    half8 v10 = *(const half8*)(vt0 + (n + 16) * SEQ + quad * 8);
    half8 v11 = *(const half8*)(vt0 + (n + 16) * SEQ + 32 + quad * 8);

    o0 = __builtin_amdgcn_mfma_f32_16x16x32_f16(a0, v00, o0, 0, 0, 0);
    o0 = __builtin_amdgcn_mfma_f32_16x16x32_f16(a1, v01, o0, 0, 0, 0);
    o1 = __builtin_amdgcn_mfma_f32_16x16x32_f16(a0, v10, o1, 0, 0, 0);
    o1 = __builtin_amdgcn_mfma_f32_16x16x32_f16(a1, v11, o1, 0, 0, 0);
    ol = __builtin_amdgcn_mfma_f32_16x16x32_f16(a0, bone, ol, 0, 0, 0);
    ol = __builtin_amdgcn_mfma_f32_16x16x32_f16(a1, bone, ol, 0, 0, 0);
  }

  // publish per-wave partials
#pragma unroll
  for (int r = 0; r < 4; ++r) {
    int row = quad * 4 + r;
    Om[w][row][n]      = o0[r];
    Om[w][row][n + 16] = o1[r];
  }
  if (n == 0) {
#pragma unroll
    for (int r = 0; r < 4; ++r) Lm[w][quad * 4 + r] = ol[r];
  }
  if (quad == 0) Mm[w][n] = mr;
  __syncthreads();

  // block-level merge of 4 waves -> one unnormalized partial (O, m, l) per block
#pragma unroll
  for (int e = t; e < 512; e += 256) {
    int row = e >> 5, d = e & 31;
    float m0 = Mm[0][row], m1 = Mm[1][row], m2 = Mm[2][row], m3 = Mm[3][row];
    float ms = fmaxf(fmaxf(m0, m1), fmaxf(m2, m3));
    float w0 = __builtin_amdgcn_exp2f(m0 - ms);
    float w1 = __builtin_amdgcn_exp2f(m1 - ms);
    float w2 = __builtin_amdgcn_exp2f(m2 - ms);
    float w3 = __builtin_amdgcn_exp2f(m3 - ms);
    float L = w0 * Lm[0][row] + w1 * Lm[1][row] + w2 * Lm[2][row] + w3 * Lm[3][row];
    float O = w0 * Om[0][row][d] + w1 * Om[1][row][d] + w2 * Om[2][row][d] + w3 * Om[3][row][d];
    Op[(size_t)blockIdx.x * 512 + row * 32 + d] = O;
    if (d == 0) { Mp[blockIdx.x * 16 + row] = ms; Lp[blockIdx.x * 16 + row] = L; }
  }
}

// ---------------- Kernel 3: merge the 2 key-halves, normalize, scale ----------------
__global__ __launch_bounds__(256) void combine_kernel(const float* __restrict__ Op,
                                                      const float* __restrict__ Mp,
                                                      const float* __restrict__ Lp,
                                                      float* __restrict__ out) {
  int gid = blockIdx.x * 256 + threadIdx.x;   // [0, 524288)
  int d = gid & 31, row = gid >> 5;
  int qt = row >> 4, rin = row & 15;
  int p0 = qt, p1 = qt + 1024;
  float m0 = Mp[p0 * 16 + rin], m1 = Mp[p1 * 16 + rin];
  float ms = fmaxf(m0, m1);
  float w0 = __builtin_amdgcn_exp2f(m0 - ms);
  float w1 = __builtin_amdgcn_exp2f(m1 - ms);
  float L = w0 * Lp[p0 * 16 + rin] + w1 * Lp[p1 * 16 + rin];
  float O = w0 * Op[(size_t)p0 * 512 + rin * 32 + d] + w1 * Op[(size_t)p1 * 512 + rin * 32 + d];
  out[row * HD + d] = O * SCALING / L;
}

extern "C" void kernel_launch(void* const* d_in, const int* in_sizes, int n_in,
                              void* d_out, int out_size, void* d_ws, size_t ws_size,
                              hipStream_t stream) {
  const float* x  = (const float*)d_in[0];
  const float* Wq = (const float*)d_in[1];
  const float* Wk = (const float*)d_in[2];
  const float* Wv = (const float*)d_in[3];
  float* out = (float*)d_out;

  _Float16* wsw = (_Float16*)d_ws;          // 24576 halves
  _Float16* qw  = wsw + 24576;              // [16384][32]
  _Float16* kw  = qw + 16384 * HD;          // [16384][32]
  _Float16* vt  = kw + 16384 * HD;          // [4][32][4096]
  float* Op = (float*)(vt + 16384 * HD);    // [2048][16][32]
  float* Mp = Op + 2048 * 512;              // [2048][16]
  float* Lp = Mp + 2048 * 16;               // [2048][16]

  prep_kernel<<<96, 256, 0, stream>>>(Wq, Wk, Wv, wsw);
  qkv_kernel<<<256, 256, 0, stream>>>(x, wsw, qw, kw, vt);
  attn_kernel<<<2048, 256, 0, stream>>>(qw, kw, vt, Op, Mp, Lp);
  combine_kernel<<<2048, 256, 0, stream>>>(Op, Mp, Lp, out);
}

// Round 5
// 114.043 us; speedup vs baseline: 1.8869x; 1.0814x over previous
//
#include <hip/hip_runtime.h>

#define EMB 256
#define HD 32
#define SEQ 4096
#define NSPLIT 8      // key splits across blocks
#define KRANGE 512    // keys per block (shared by its 4 waves)
#define NQROW 16384   // B*S

typedef _Float16 half8 __attribute__((ext_vector_type(8)));
typedef float floatx4 __attribute__((ext_vector_type(4)));

#define L2E 1.44269504088896340736f
#define SCALING 0.17677669529663687f   // 32^-0.5, applied POST-softmax

// ---- in-register 16x16 f16-pair transpose step via ds_bpermute (ISA-verified pull semantics) ----
// Inputs x,y: packed f16 pairs; lane(n,quad) holds keys {4q,4q+1} of group gx / gy.
// Outputs: o0 = [x@q0, x@q2, y@q0, y@q2] per quad, o1 = [x@q1, x@q3, y@q1, y@q3].
__device__ __forceinline__ void xpose2(unsigned x, unsigned y, unsigned& o0, unsigned& o1) {
  int lane = threadIdx.x & 63;
  int n = lane & 15, quad = lane >> 4;
  int a0 = (n + 32 * (quad & 1)) << 2;        // q0/q2 source lanes
  int a1 = (n + 16 + 32 * (quad & 1)) << 2;   // q1/q3 source lanes
  unsigned t0 = (unsigned)__builtin_amdgcn_ds_bpermute(a0, (int)x);
  unsigned t1 = (unsigned)__builtin_amdgcn_ds_bpermute(a0, (int)y);
  o0 = (quad < 2) ? t0 : t1;
  unsigned t2 = (unsigned)__builtin_amdgcn_ds_bpermute(a1, (int)x);
  unsigned t3 = (unsigned)__builtin_amdgcn_ds_bpermute(a1, (int)y);
  o1 = (quad < 2) ? t2 : t3;
}

// max across the 4 quads (lanes n, n+16, n+32, n+48) — verified shfl pattern (R1/R2)
__device__ __forceinline__ float crossmax(float x) {
  x = fmaxf(x, __shfl_xor(x, 16));
  return fmaxf(x, __shfl_xor(x, 32));
}

__device__ __forceinline__ half8 mk8(unsigned a, unsigned b, unsigned c, unsigned d) {
  union { unsigned u[4]; half8 h; } z;
  z.u[0] = a; z.u[1] = b; z.u[2] = c; z.u[3] = d;
  return z.h;
}

// ---------------- Kernel 0: swizzle W into MFMA B-frag order (f16), Wq pre-scaled by L2E ----------------
__global__ __launch_bounds__(256) void prep_kernel(const float* __restrict__ Wq,
                                                   const float* __restrict__ Wk,
                                                   const float* __restrict__ Wv,
                                                   _Float16* __restrict__ wsw) {
  int gid = blockIdx.x * 256 + threadIdx.x;   // [0, 24576)
  int j    = gid & 7;
  int lane = (gid >> 3) & 63;
  int kc   = (gid >> 9) & 7;
  int half = (gid >> 12) & 1;
  int mat  = gid >> 13;
  const float* W = (mat == 0) ? Wq : ((mat == 1) ? Wk : Wv);
  int n = lane & 15, quad = lane >> 4;
  int e = kc * 32 + quad * 8 + j;
  int d = n + half * 16;
  float v = W[e * HD + d];
  if (mat == 0) v *= L2E;                     // exp2-domain scores for free
  wsw[gid] = (_Float16)v;
}

// ---------------- Kernel 1: QKV projection, one pass over x ----------------
__global__ __launch_bounds__(256) void qkv_kernel(const float* __restrict__ x,
                                                  const _Float16* __restrict__ wsw,
                                                  _Float16* __restrict__ qw,
                                                  _Float16* __restrict__ kw,
                                                  _Float16* __restrict__ vt) {
  int lane = threadIdx.x & 63, wave = threadIdx.x >> 6;
  int n = lane & 15, quad = lane >> 4;
  int rowbase = blockIdx.x * 64 + wave * 16;

  floatx4 c[3][2];
#pragma unroll
  for (int m = 0; m < 3; ++m)
#pragma unroll
    for (int h = 0; h < 2; ++h) c[m][h] = (floatx4){0, 0, 0, 0};

#pragma unroll
  for (int kc = 0; kc < 8; ++kc) {
    const float* xp = x + (rowbase + n) * EMB + kc * 32 + quad * 8;
    float4 xa = *(const float4*)(xp);
    float4 xb = *(const float4*)(xp + 4);
    half8 a;
    a[0] = (_Float16)xa.x; a[1] = (_Float16)xa.y; a[2] = (_Float16)xa.z; a[3] = (_Float16)xa.w;
    a[4] = (_Float16)xb.x; a[5] = (_Float16)xb.y; a[6] = (_Float16)xb.z; a[7] = (_Float16)xb.w;
#pragma unroll
    for (int m = 0; m < 3; ++m)
#pragma unroll
      for (int h = 0; h < 2; ++h) {
        half8 bb = *(const half8*)(wsw + (((m * 2 + h) * 8 + kc) << 9) + (lane << 3));
        c[m][h] = __builtin_amdgcn_mfma_f32_16x16x32_f16(a, bb, c[m][h], 0, 0, 0);
      }
  }

#pragma unroll
  for (int r = 0; r < 4; ++r) {
    int row = rowbase + quad * 4 + r;
    qw[row * HD + n]      = (_Float16)c[0][0][r];
    qw[row * HD + n + 16] = (_Float16)c[0][1][r];
    kw[row * HD + n]      = (_Float16)c[1][0][r];
    kw[row * HD + n + 16] = (_Float16)c[1][1][r];
  }
  int b = rowbase >> 12;
  int s0 = rowbase & (SEQ - 1);
  _Float16* vb = vt + b * HD * SEQ;
#pragma unroll
  for (int r = 0; r < 4; ++r) {
    int s = s0 + quad * 4 + r;
    vb[n * SEQ + s]        = (_Float16)c[2][0][r];
    vb[(n + 16) * SEQ + s] = (_Float16)c[2][1][r];
  }
}

// ---------------- Kernel 2: flash attention — no LDS storage, O^T orientation ----------------
// 1024 blocks x 256 thr. Block = 4 waves sharing keys [sp*512, sp*512+512), wave w owns
// q-rows qb*128 + w*32. S^T = K·Q^T (2 chains of 16 q-cols); P transposed to B-frags via
// ds_bpermute; O^T = V^T·P^T; l via ones-row MFMA. Only global loads + crossbar in the loop.
__global__ __launch_bounds__(256) void attn_kernel(const _Float16* __restrict__ q,
                                                   const _Float16* __restrict__ k,
                                                   const _Float16* __restrict__ vt,
                                                   float* __restrict__ Op,
                                                   float* __restrict__ Mp,
                                                   float* __restrict__ Lp) {
  const int t = threadIdx.x;
  const int w = t >> 6, lane = t & 63;
  const int n = lane & 15, quad = lane >> 4;
  const int qb = blockIdx.x & 127;
  const int sp = blockIdx.x >> 7;
  const int b = qb >> 5;
  const int qrow0 = qb * 128 + w * 32;
  const int key0 = sp * KRANGE;

  const _Float16* kb = k  + (size_t)(b * SEQ + key0) * HD;
  const _Float16* vb = vt + (size_t)b * HD * SEQ + key0;

  // Q B-frags (q pre-scaled by L2E): B[kk=quad*8+j][nn=n]
  half8 qf0 = *(const half8*)(q + (qrow0 + n) * HD + quad * 8);
  half8 qf1 = *(const half8*)(q + (qrow0 + 16 + n) * HD + quad * 8);

  half8 aone = {0,0,0,0,0,0,0,0};   // A ones-row (m=0) -> l lands in C row 0
  if (n == 0) { aone[0]=1; aone[1]=1; aone[2]=1; aone[3]=1; aone[4]=1; aone[5]=1; aone[6]=1; aone[7]=1; }

  floatx4 o00 = {0,0,0,0}, o01 = {0,0,0,0};   // chain0: d 0-15 / 16-31
  floatx4 o10 = {0,0,0,0}, o11 = {0,0,0,0};   // chain1
  floatx4 l0 = {0,0,0,0}, l1 = {0,0,0,0};
  float m0 = -__builtin_huge_valf(), m1 = -__builtin_huge_valf();
  const floatx4 zero = {0,0,0,0};

#pragma unroll 2
  for (int kt = 0; kt < KRANGE / 64; ++kt) {
    const _Float16* kt0 = kb + kt * 64 * HD;
    const _Float16* vt0 = vb + kt * 64;
    // K A-frags (m=key), 1KB contiguous per instr
    half8 ka0 = *(const half8*)(kt0 + (n)      * HD + quad * 8);
    half8 ka1 = *(const half8*)(kt0 + (16 + n) * HD + quad * 8);
    half8 ka2 = *(const half8*)(kt0 + (32 + n) * HD + quad * 8);
    half8 ka3 = *(const half8*)(kt0 + (48 + n) * HD + quad * 8);
    // V^T A-frags: va[keyhalf][dhalf]
    half8 va00 = *(const half8*)(vt0 + (n)      * SEQ + quad * 8);
    half8 va01 = *(const half8*)(vt0 + (16 + n) * SEQ + quad * 8);
    half8 va10 = *(const half8*)(vt0 + (n)      * SEQ + 32 + quad * 8);
    half8 va11 = *(const half8*)(vt0 + (16 + n) * SEQ + 32 + quad * 8);

    floatx4 s0[4], s1[4];
    s0[0] = __builtin_amdgcn_mfma_f32_16x16x32_f16(ka0, qf0, zero, 0, 0, 0);
    s0[1] = __builtin_amdgcn_mfma_f32_16x16x32_f16(ka1, qf0, zero, 0, 0, 0);
    s0[2] = __builtin_amdgcn_mfma_f32_16x16x32_f16(ka2, qf0, zero, 0, 0, 0);
    s0[3] = __builtin_amdgcn_mfma_f32_16x16x32_f16(ka3, qf0, zero, 0, 0, 0);
    s1[0] = __builtin_amdgcn_mfma_f32_16x16x32_f16(ka0, qf1, zero, 0, 0, 0);
    s1[1] = __builtin_amdgcn_mfma_f32_16x16x32_f16(ka1, qf1, zero, 0, 0, 0);
    s1[2] = __builtin_amdgcn_mfma_f32_16x16x32_f16(ka2, qf1, zero, 0, 0, 0);
    s1[3] = __builtin_amdgcn_mfma_f32_16x16x32_f16(ka3, qf1, zero, 0, 0, 0);

    half8 B00, B01, B10, B11;   // B[chain][keyhalf]
#pragma unroll
    for (int c = 0; c < 2; ++c) {
      floatx4* sv = c ? s1 : s0;
      float& mr = c ? m1 : m0;
      floatx4 t01 = __builtin_elementwise_max(sv[0], sv[1]);
      floatx4 t23 = __builtin_elementwise_max(sv[2], sv[3]);
      floatx4 t4  = __builtin_elementwise_max(t01, t23);
      float mm = fmaxf(fmaxf(t4[0], t4[1]), fmaxf(t4[2], t4[3]));
      mm = crossmax(mm);
      float mnew = fmaxf(mr, mm);
      float alpha = __builtin_amdgcn_exp2f(mr - mnew);
      mr = mnew;

      unsigned pk[4][2];
#pragma unroll
      for (int g = 0; g < 4; ++g) {
        float p0 = __builtin_amdgcn_exp2f(sv[g][0] - mnew);
        float p1 = __builtin_amdgcn_exp2f(sv[g][1] - mnew);
        float p2 = __builtin_amdgcn_exp2f(sv[g][2] - mnew);
        float p3 = __builtin_amdgcn_exp2f(sv[g][3] - mnew);
        pk[g][0] = __builtin_bit_cast(unsigned, __builtin_amdgcn_cvt_pkrtz(p0, p1));
        pk[g][1] = __builtin_bit_cast(unsigned, __builtin_amdgcn_cvt_pkrtz(p2, p3));
      }
      unsigned b00, b02, b01, b03, b10, b12, b11, b13;
      xpose2(pk[0][0], pk[1][0], b00, b02);
      xpose2(pk[0][1], pk[1][1], b01, b03);
      xpose2(pk[2][0], pk[3][0], b10, b12);
      xpose2(pk[2][1], pk[3][1], b11, b13);
      if (c == 0) {
        B00 = mk8(b00, b01, b02, b03); B01 = mk8(b10, b11, b12, b13);
        o00 *= alpha; o01 *= alpha; l0[0] *= alpha;
      } else {
        B10 = mk8(b00, b01, b02, b03); B11 = mk8(b10, b11, b12, b13);
        o10 *= alpha; o11 *= alpha; l1[0] *= alpha;
      }
    }

    o00 = __builtin_amdgcn_mfma_f32_16x16x32_f16(va00, B00, o00, 0, 0, 0);
    o00 = __builtin_amdgcn_mfma_f32_16x16x32_f16(va10, B01, o00, 0, 0, 0);
    o01 = __builtin_amdgcn_mfma_f32_16x16x32_f16(va01, B00, o01, 0, 0, 0);
    o01 = __builtin_amdgcn_mfma_f32_16x16x32_f16(va11, B01, o01, 0, 0, 0);
    l0  = __builtin_amdgcn_mfma_f32_16x16x32_f16(aone, B00, l0, 0, 0, 0);
    l0  = __builtin_amdgcn_mfma_f32_16x16x32_f16(aone, B01, l0, 0, 0, 0);

    o10 = __builtin_amdgcn_mfma_f32_16x16x32_f16(va00, B10, o10, 0, 0, 0);
    o10 = __builtin_amdgcn_mfma_f32_16x16x32_f16(va10, B11, o10, 0, 0, 0);
    o11 = __builtin_amdgcn_mfma_f32_16x16x32_f16(va01, B10, o11, 0, 0, 0);
    o11 = __builtin_amdgcn_mfma_f32_16x16x32_f16(va11, B11, o11, 0, 0, 0);
    l1  = __builtin_amdgcn_mfma_f32_16x16x32_f16(aone, B10, l1, 0, 0, 0);
    l1  = __builtin_amdgcn_mfma_f32_16x16x32_f16(aone, B11, l1, 0, 0, 0);
  }

  // epilogue: O^T C-layout -> out[q][d] partials, float4 per store
  size_t obase = ((size_t)(sp * NQROW + qrow0)) * 32;
  *(floatx4*)&Op[obase + (size_t)n * 32 + quad * 4]             = o00;
  *(floatx4*)&Op[obase + (size_t)n * 32 + 16 + quad * 4]        = o01;
  *(floatx4*)&Op[obase + (size_t)(16 + n) * 32 + quad * 4]      = o10;
  *(floatx4*)&Op[obase + (size_t)(16 + n) * 32 + 16 + quad * 4] = o11;
  if (quad == 0) {
    int mi = sp * NQROW + qrow0;
    Mp[mi + n]      = m0;
    Mp[mi + 16 + n] = m1;
    Lp[mi + n]      = l0[0];    // C row 0 lives in quad-0 lanes, reg 0
    Lp[mi + 16 + n] = l1[0];
  }
}

// ---------------- Kernel 3: merge the 8 key-splits, normalize, scale ----------------
__global__ __launch_bounds__(256) void combine_kernel(const float* __restrict__ Op,
                                                      const float* __restrict__ Mp,
                                                      const float* __restrict__ Lp,
                                                      float* __restrict__ out) {
  int gid = blockIdx.x * 256 + threadIdx.x;   // [0, 524288)
  int d = gid & 31, qrow = gid >> 5;
  float mv[NSPLIT];
  float ms = -__builtin_huge_valf();
#pragma unroll
  for (int sp = 0; sp < NSPLIT; ++sp) {
    mv[sp] = Mp[sp * NQROW + qrow];
    ms = fmaxf(ms, mv[sp]);
  }
  float L = 0.f, O = 0.f;
#pragma unroll
  for (int sp = 0; sp < NSPLIT; ++sp) {
    float ww = __builtin_amdgcn_exp2f(mv[sp] - ms);
    L += ww * Lp[sp * NQROW + qrow];
    O += ww * Op[((size_t)(sp * NQROW + qrow)) * 32 + d];
  }
  out[gid] = O * SCALING / L;
}

extern "C" void kernel_launch(void* const* d_in, const int* in_sizes, int n_in,
                              void* d_out, int out_size, void* d_ws, size_t ws_size,
                              hipStream_t stream) {
  const float* x  = (const float*)d_in[0];
  const float* Wq = (const float*)d_in[1];
  const float* Wk = (const float*)d_in[2];
  const float* Wv = (const float*)d_in[3];
  float* out = (float*)d_out;

  _Float16* wsw = (_Float16*)d_ws;          // 24576 f16
  _Float16* qw  = wsw + 24576;              // [16384][32]
  _Float16* kw  = qw + NQROW * HD;          // [16384][32]
  _Float16* vt  = kw + NQROW * HD;          // [4][32][4096]
  float* Op = (float*)(vt + NQROW * HD);    // [8][16384][32]  (16 MB)
  float* Mp = Op + (size_t)NSPLIT * NQROW * 32;  // [8][16384]
  float* Lp = Mp + NSPLIT * NQROW;               // [8][16384]

  prep_kernel<<<96, 256, 0, stream>>>(Wq, Wk, Wv, wsw);
  qkv_kernel<<<256, 256, 0, stream>>>(x, wsw, qw, kw, vt);
  attn_kernel<<<1024, 256, 0, stream>>>(qw, kw, vt, Op, Mp, Lp);
  combine_kernel<<<2048, 256, 0, stream>>>(Op, Mp, Lp, out);
}

// Round 6
// 106.010 us; speedup vs baseline: 2.0299x; 1.0758x over previous
//
#include <hip/hip_runtime.h>

#define EMB 256
#define HD 32
#define SEQ 4096
#define NSPLIT 8      // key splits across blocks
#define KRANGE 512    // keys per block (shared by its 4 waves)
#define NQROW 16384   // B*S

typedef _Float16 half8 __attribute__((ext_vector_type(8)));
typedef _Float16 half4v __attribute__((ext_vector_type(4)));
typedef float floatx4 __attribute__((ext_vector_type(4)));

#define L2E 1.44269504088896340736f
#define SCALING 0.17677669529663687f   // 32^-0.5, applied POST-softmax

// ---- in-register 16x16 f16-pair transpose step via ds_bpermute (HW-verified R4) ----
__device__ __forceinline__ void xpose2(unsigned x, unsigned y, unsigned& o0, unsigned& o1) {
  int lane = threadIdx.x & 63;
  int n = lane & 15, quad = lane >> 4;
  int a0 = (n + 32 * (quad & 1)) << 2;        // q0/q2 source lanes
  int a1 = (n + 16 + 32 * (quad & 1)) << 2;   // q1/q3 source lanes
  unsigned t0 = (unsigned)__builtin_amdgcn_ds_bpermute(a0, (int)x);
  unsigned t1 = (unsigned)__builtin_amdgcn_ds_bpermute(a0, (int)y);
  o0 = (quad < 2) ? t0 : t1;
  unsigned t2 = (unsigned)__builtin_amdgcn_ds_bpermute(a1, (int)x);
  unsigned t3 = (unsigned)__builtin_amdgcn_ds_bpermute(a1, (int)y);
  o1 = (quad < 2) ? t2 : t3;
}

__device__ __forceinline__ float crossmax(float x) {
  x = fmaxf(x, __shfl_xor(x, 16));
  return fmaxf(x, __shfl_xor(x, 32));
}

__device__ __forceinline__ half8 mk8(unsigned a, unsigned b, unsigned c, unsigned d) {
  union { unsigned u[4]; half8 h; } z;
  z.u[0] = a; z.u[1] = b; z.u[2] = c; z.u[3] = d;
  return z.h;
}

// ---------------- Kernel 0: swizzle W into MFMA B-frag order (f16), Wq pre-scaled by L2E ----------------
__global__ __launch_bounds__(256) void prep_kernel(const float* __restrict__ Wq,
                                                   const float* __restrict__ Wk,
                                                   const float* __restrict__ Wv,
                                                   _Float16* __restrict__ wsw) {
  int gid = blockIdx.x * 256 + threadIdx.x;   // [0, 24576)
  int j    = gid & 7;
  int lane = (gid >> 3) & 63;
  int kc   = (gid >> 9) & 7;
  int half = (gid >> 12) & 1;
  int mat  = gid >> 13;
  const float* W = (mat == 0) ? Wq : ((mat == 1) ? Wk : Wv);
  int n = lane & 15, quad = lane >> 4;
  int e = kc * 32 + quad * 8 + j;
  int d = n + half * 16;
  float v = W[e * HD + d];
  if (mat == 0) v *= L2E;                     // exp2-domain scores for free
  wsw[gid] = (_Float16)v;
}

// ---------------- Kernel 1: QKV projection, split by matrix (grid 256 x 3) ----------------
// 12 waves/CU for latency hiding; x re-reads served by L2/L3.
__global__ __launch_bounds__(256) void qkv_kernel(const float* __restrict__ x,
                                                  const _Float16* __restrict__ wsw,
                                                  _Float16* __restrict__ qw,
                                                  _Float16* __restrict__ kw,
                                                  _Float16* __restrict__ vt) {
  int lane = threadIdx.x & 63, wave = threadIdx.x >> 6;
  int n = lane & 15, quad = lane >> 4;
  int mat = blockIdx.y;
  int rowbase = blockIdx.x * 64 + wave * 16;

  floatx4 c0 = {0,0,0,0}, c1 = {0,0,0,0};

#pragma unroll
  for (int kc = 0; kc < 8; ++kc) {
    const float* xp = x + (rowbase + n) * EMB + kc * 32 + quad * 8;
    float4 xa = *(const float4*)(xp);
    float4 xb = *(const float4*)(xp + 4);
    half8 a;
    a[0] = (_Float16)xa.x; a[1] = (_Float16)xa.y; a[2] = (_Float16)xa.z; a[3] = (_Float16)xa.w;
    a[4] = (_Float16)xb.x; a[5] = (_Float16)xb.y; a[6] = (_Float16)xb.z; a[7] = (_Float16)xb.w;
    half8 b0 = *(const half8*)(wsw + (((mat * 2 + 0) * 8 + kc) << 9) + (lane << 3));
    half8 b1 = *(const half8*)(wsw + (((mat * 2 + 1) * 8 + kc) << 9) + (lane << 3));
    c0 = __builtin_amdgcn_mfma_f32_16x16x32_f16(a, b0, c0, 0, 0, 0);
    c1 = __builtin_amdgcn_mfma_f32_16x16x32_f16(a, b1, c1, 0, 0, 0);
  }

  if (mat == 2) {
    int b = rowbase >> 12;
    int s0 = rowbase & (SEQ - 1);
    _Float16* vb = vt + b * HD * SEQ;
#pragma unroll
    for (int r = 0; r < 4; ++r) {
      int s = s0 + quad * 4 + r;
      vb[n * SEQ + s]        = (_Float16)c0[r];
      vb[(n + 16) * SEQ + s] = (_Float16)c1[r];
    }
  } else {
    _Float16* dst = (mat == 0) ? qw : kw;
#pragma unroll
    for (int r = 0; r < 4; ++r) {
      int row = rowbase + quad * 4 + r;
      dst[row * HD + n]      = (_Float16)c0[r];
      dst[row * HD + n + 16] = (_Float16)c1[r];
    }
  }
}

// ---------------- Kernel 2: flash attention — no LDS storage, O^T orientation ----------------
// 1024 blocks x 256 thr = exactly 4 blocks/CU at 4 waves/SIMD. Wave owns 32 q-rows,
// block's 4 waves share keys [sp*512, +512). Full unroll over the 8 key-tiles.
__global__ __launch_bounds__(256, 4) void attn_kernel(const _Float16* __restrict__ q,
                                                      const _Float16* __restrict__ k,
                                                      const _Float16* __restrict__ vt,
                                                      _Float16* __restrict__ Op,
                                                      float* __restrict__ Mp,
                                                      float* __restrict__ Lp) {
  const int t = threadIdx.x;
  const int w = t >> 6, lane = t & 63;
  const int n = lane & 15, quad = lane >> 4;
  const int qb = blockIdx.x & 127;
  const int sp = blockIdx.x >> 7;
  const int b = qb >> 5;
  const int qrow0 = qb * 128 + w * 32;
  const int key0 = sp * KRANGE;

  const _Float16* kb = k  + (size_t)(b * SEQ + key0) * HD;
  const _Float16* vb = vt + (size_t)b * HD * SEQ + key0;

  // Q B-frags (pre-scaled by L2E): B[kk=quad*8+j][nn=n]
  half8 qf0 = *(const half8*)(q + (qrow0 + n) * HD + quad * 8);
  half8 qf1 = *(const half8*)(q + (qrow0 + 16 + n) * HD + quad * 8);

  half8 aone = {0,0,0,0,0,0,0,0};   // A ones-row (m=0) -> l lands in C row 0
  if (n == 0) { aone[0]=1; aone[1]=1; aone[2]=1; aone[3]=1; aone[4]=1; aone[5]=1; aone[6]=1; aone[7]=1; }

  floatx4 o00 = {0,0,0,0}, o01 = {0,0,0,0};   // chain0: d 0-15 / 16-31
  floatx4 o10 = {0,0,0,0}, o11 = {0,0,0,0};   // chain1
  floatx4 l0 = {0,0,0,0}, l1 = {0,0,0,0};
  float m0 = -__builtin_huge_valf(), m1 = -__builtin_huge_valf();
  const floatx4 zero = {0,0,0,0};

#pragma unroll
  for (int kt = 0; kt < KRANGE / 64; ++kt) {
    const _Float16* kt0 = kb + kt * 64 * HD;
    const _Float16* vt0 = vb + kt * 64;
    half8 ka0 = *(const half8*)(kt0 + (n)      * HD + quad * 8);
    half8 ka1 = *(const half8*)(kt0 + (16 + n) * HD + quad * 8);
    half8 ka2 = *(const half8*)(kt0 + (32 + n) * HD + quad * 8);
    half8 ka3 = *(const half8*)(kt0 + (48 + n) * HD + quad * 8);
    half8 va00 = *(const half8*)(vt0 + (n)      * SEQ + quad * 8);
    half8 va01 = *(const half8*)(vt0 + (16 + n) * SEQ + quad * 8);
    half8 va10 = *(const half8*)(vt0 + (n)      * SEQ + 32 + quad * 8);
    half8 va11 = *(const half8*)(vt0 + (16 + n) * SEQ + 32 + quad * 8);

    floatx4 s0[4], s1[4];
    s0[0] = __builtin_amdgcn_mfma_f32_16x16x32_f16(ka0, qf0, zero, 0, 0, 0);
    s0[1] = __builtin_amdgcn_mfma_f32_16x16x32_f16(ka1, qf0, zero, 0, 0, 0);
    s0[2] = __builtin_amdgcn_mfma_f32_16x16x32_f16(ka2, qf0, zero, 0, 0, 0);
    s0[3] = __builtin_amdgcn_mfma_f32_16x16x32_f16(ka3, qf0, zero, 0, 0, 0);
    s1[0] = __builtin_amdgcn_mfma_f32_16x16x32_f16(ka0, qf1, zero, 0, 0, 0);
    s1[1] = __builtin_amdgcn_mfma_f32_16x16x32_f16(ka1, qf1, zero, 0, 0, 0);
    s1[2] = __builtin_amdgcn_mfma_f32_16x16x32_f16(ka2, qf1, zero, 0, 0, 0);
    s1[3] = __builtin_amdgcn_mfma_f32_16x16x32_f16(ka3, qf1, zero, 0, 0, 0);

    half8 B00, B01, B10, B11;   // B[chain][keyhalf]
#pragma unroll
    for (int c = 0; c < 2; ++c) {
      floatx4* sv = c ? s1 : s0;
      float& mr = c ? m1 : m0;
      floatx4 t01 = __builtin_elementwise_max(sv[0], sv[1]);
      floatx4 t23 = __builtin_elementwise_max(sv[2], sv[3]);
      floatx4 t4  = __builtin_elementwise_max(t01, t23);
      float mm = fmaxf(fmaxf(t4[0], t4[1]), fmaxf(t4[2], t4[3]));
      mm = crossmax(mm);
      float mnew = fmaxf(mr, mm);
      float alpha = __builtin_amdgcn_exp2f(mr - mnew);
      mr = mnew;

      unsigned pk[4][2];
#pragma unroll
      for (int g = 0; g < 4; ++g) {
        float p0 = __builtin_amdgcn_exp2f(sv[g][0] - mnew);
        float p1 = __builtin_amdgcn_exp2f(sv[g][1] - mnew);
        float p2 = __builtin_amdgcn_exp2f(sv[g][2] - mnew);
        float p3 = __builtin_amdgcn_exp2f(sv[g][3] - mnew);
        pk[g][0] = __builtin_bit_cast(unsigned, __builtin_amdgcn_cvt_pkrtz(p0, p1));
        pk[g][1] = __builtin_bit_cast(unsigned, __builtin_amdgcn_cvt_pkrtz(p2, p3));
      }
      unsigned b00, b02, b01, b03, b10, b12, b11, b13;
      xpose2(pk[0][0], pk[1][0], b00, b02);
      xpose2(pk[0][1], pk[1][1], b01, b03);
      xpose2(pk[2][0], pk[3][0], b10, b12);
      xpose2(pk[2][1], pk[3][1], b11, b13);
      if (c == 0) {
        B00 = mk8(b00, b01, b02, b03); B01 = mk8(b10, b11, b12, b13);
        o00 *= alpha; o01 *= alpha; l0[0] *= alpha;
      } else {
        B10 = mk8(b00, b01, b02, b03); B11 = mk8(b10, b11, b12, b13);
        o10 *= alpha; o11 *= alpha; l1[0] *= alpha;
      }
    }

    o00 = __builtin_amdgcn_mfma_f32_16x16x32_f16(va00, B00, o00, 0, 0, 0);
    o00 = __builtin_amdgcn_mfma_f32_16x16x32_f16(va10, B01, o00, 0, 0, 0);
    o01 = __builtin_amdgcn_mfma_f32_16x16x32_f16(va01, B00, o01, 0, 0, 0);
    o01 = __builtin_amdgcn_mfma_f32_16x16x32_f16(va11, B01, o01, 0, 0, 0);
    l0  = __builtin_amdgcn_mfma_f32_16x16x32_f16(aone, B00, l0, 0, 0, 0);
    l0  = __builtin_amdgcn_mfma_f32_16x16x32_f16(aone, B01, l0, 0, 0, 0);

    o10 = __builtin_amdgcn_mfma_f32_16x16x32_f16(va00, B10, o10, 0, 0, 0);
    o10 = __builtin_amdgcn_mfma_f32_16x16x32_f16(va10, B11, o10, 0, 0, 0);
    o11 = __builtin_amdgcn_mfma_f32_16x16x32_f16(va01, B10, o11, 0, 0, 0);
    o11 = __builtin_amdgcn_mfma_f32_16x16x32_f16(va11, B11, o11, 0, 0, 0);
    l1  = __builtin_amdgcn_mfma_f32_16x16x32_f16(aone, B10, l1, 0, 0, 0);
    l1  = __builtin_amdgcn_mfma_f32_16x16x32_f16(aone, B11, l1, 0, 0, 0);
  }

  // epilogue: O^T C-layout -> Op[sp][qrow][d] f16 partials (8B stores)
  // lane(n,quad): chain0 -> qrow qrow0+n, d = quad*4..+3 (o00) and 16+quad*4..+3 (o01)
  half4v p00, p01, p10, p11;
#pragma unroll
  for (int r = 0; r < 4; ++r) {
    p00[r] = (_Float16)o00[r]; p01[r] = (_Float16)o01[r];
    p10[r] = (_Float16)o10[r]; p11[r] = (_Float16)o11[r];
  }
  size_t obase = ((size_t)(sp * NQROW + qrow0)) * 32;
  *(half4v*)&Op[obase + (size_t)n * 32 + quad * 4]             = p00;
  *(half4v*)&Op[obase + (size_t)n * 32 + 16 + quad * 4]        = p01;
  *(half4v*)&Op[obase + (size_t)(16 + n) * 32 + quad * 4]      = p10;
  *(half4v*)&Op[obase + (size_t)(16 + n) * 32 + 16 + quad * 4] = p11;
  if (quad == 0) {
    int mi = sp * NQROW + qrow0;
    Mp[mi + n]      = m0;
    Mp[mi + 16 + n] = m1;
    Lp[mi + n]      = l0[0];    // C row 0 = quad-0 lanes, reg 0
    Lp[mi + 16 + n] = l1[0];
  }
}

// ---------------- Kernel 3: merge the 8 key-splits, normalize, scale ----------------
// thread handles (qrow, 4-wide d chunk): half4 loads, float4 store.
__global__ __launch_bounds__(256) void combine_kernel(const _Float16* __restrict__ Op,
                                                      const float* __restrict__ Mp,
                                                      const float* __restrict__ Lp,
                                                      float* __restrict__ out) {
  int gid = blockIdx.x * 256 + threadIdx.x;   // [0, 131072)
  int dc = gid & 7, qrow = gid >> 3;
  float mv[NSPLIT];
  float ms = -__builtin_huge_valf();
#pragma unroll
  for (int sp = 0; sp < NSPLIT; ++sp) {
    mv[sp] = Mp[sp * NQROW + qrow];
    ms = fmaxf(ms, mv[sp]);
  }
  float L = 0.f;
  floatx4 O = {0.f, 0.f, 0.f, 0.f};
#pragma unroll
  for (int sp = 0; sp < NSPLIT; ++sp) {
    float ww = __builtin_amdgcn_exp2f(mv[sp] - ms);
    L += ww * Lp[sp * NQROW + qrow];
    half4v ov = *(const half4v*)&Op[((size_t)(sp * NQROW + qrow)) * 32 + dc * 4];
#pragma unroll
    for (int r = 0; r < 4; ++r) O[r] += ww * (float)ov[r];
  }
  float inv = SCALING / L;
  floatx4 res = {O[0] * inv, O[1] * inv, O[2] * inv, O[3] * inv};
  *(floatx4*)&out[qrow * HD + dc * 4] = res;
}

extern "C" void kernel_launch(void* const* d_in, const int* in_sizes, int n_in,
                              void* d_out, int out_size, void* d_ws, size_t ws_size,
                              hipStream_t stream) {
  const float* x  = (const float*)d_in[0];
  const float* Wq = (const float*)d_in[1];
  const float* Wk = (const float*)d_in[2];
  const float* Wv = (const float*)d_in[3];
  float* out = (float*)d_out;

  _Float16* wsw = (_Float16*)d_ws;          // 24576 f16
  _Float16* qw  = wsw + 24576;              // [16384][32]
  _Float16* kw  = qw + NQROW * HD;          // [16384][32]
  _Float16* vt  = kw + NQROW * HD;          // [4][32][4096]
  _Float16* Op  = vt + NQROW * HD;          // [8][16384][32] f16 (8 MB)
  float* Mp = (float*)(Op + (size_t)NSPLIT * NQROW * 32);  // [8][16384]
  float* Lp = Mp + NSPLIT * NQROW;                         // [8][16384]

  prep_kernel<<<96, 256, 0, stream>>>(Wq, Wk, Wv, wsw);
  qkv_kernel<<<dim3(256, 3), 256, 0, stream>>>(x, wsw, qw, kw, vt);
  attn_kernel<<<1024, 256, 0, stream>>>(qw, kw, vt, Op, Mp, Lp);
  combine_kernel<<<512, 256, 0, stream>>>(Op, Mp, Lp, out);
}